// Round 8
// baseline (271.904 us; speedup 1.0000x reference)
//
#include <hip/hip_runtime.h>
#include <math.h>

// ============================================================================
// WaveletBasis as bf16 MFMA GEMM: M=32768(B), N=64(O), K=1024*9.
// Aligned run layout: 128 runs, run R = features [8R,8R+8); run = 9 qslots
// (qslot f<8 = basis octet of feature 8R+f, qslot 8 = x-octet).
// Chunk c = runs [4c,4c+4) = 9 K32-steps.
//
// ROUND 9: round 8 (zero-barrier, A-in-register) FAILED correctness
// (absmax 8.94). Audit: all MFMA mappings pinned by rounds 3-7 passing
// kernels; the only never-verified components were (a) the rolled f20/f21
// cross-iteration x prefetch and (b) the x-slot t-split. Both reverted:
//  (a) f2 loads now direct per-iteration (lane's 4 chunk loads share one
//      128B line; L1 + 16 waves/CU TLP hide latency).
//  (b) x-slot u-split: waves ks in {0,1} own u=ks with BOTH nq fragments
//      (round-7-verified operand-role pattern: one x-octet A register vs
//      B fragments t=2u+0, t=2u+1). ks in {2,3} skip.
// Structure otherwise = round 8: wave (ks slot-pair, mh row-half); per-lane
// gen_basis builds the 32x32x16 A-fragment directly (lane=row, l>>5=k-half);
// no LDS tile, NO main-loop barriers; P[4][64][64] ks-partials reduced once.
// ============================================================================

typedef __attribute__((ext_vector_type(8))) short short8;
typedef __attribute__((ext_vector_type(4))) float f32x4;
typedef __attribute__((ext_vector_type(16))) float f32x16;

__device__ __forceinline__ unsigned int f2bf(float f) {
  unsigned int u = __float_as_uint(f);
  u += 0x7FFFu + ((u >> 16) & 1u);   // RNE; finite inputs
  return u >> 16;
}

// 4 dwords = 8 bf16 basis values (n=0..7) as a function of bucket j.
__device__ __forceinline__ void gen_basis(int j, unsigned int* d) {
  d[0] = (j < 4) ? 0x3F803F80u : 0xBF803F80u;                  // [phi=1, psi0=+-1]
  unsigned int sq1 = (j & 2) ? 0xBFB5u : 0x3FB5u;              // +-sqrt2
  d[1] = (j & 4) ? (sq1 << 16) : sq1;                          // one-hot k1=j>>2
  unsigned long long sd2 = (j & 1) ? 0xC000ull : 0x4000ull;    // +-2
  unsigned long long d23 = sd2 << ((j & 6) << 3);              // << 16*(j>>1)
  d[2] = (unsigned int)d23;
  d[3] = (unsigned int)(d23 >> 32);
}

// ---------------------------------------------------------------------------
// K1: W into 32x32x16 B-fragment order under the aligned run layout.
// Fragment (c,s,u,nq) at Bsw[((c*9+s)*4 + 2u + nq)*64 + l]: lane l holds
// col o = 32nq+(l&31), k = qslot s of run R = 4c+2u+(l>>5). Short jj:
// s<8 -> (f=8R+s, n=jj); s==8 -> (f=8R+jj, n=8 i.e. base_weight).
// (Unchanged; verified by rounds 6/7.)
// ---------------------------------------------------------------------------
__global__ __launch_bounds__(256) void build_w(const float* __restrict__ coeffs,
                                               const float* __restrict__ bw,
                                               uint4* __restrict__ Wsw) {
  const int l = threadIdx.x & 63;
  const int t = threadIdx.x >> 6;   // t = 2u+nq, 0..3
  const int g = blockIdx.x;         // 0..287
  const int c = g / 9, j = g - c * 9;
  const int u = t >> 1, nq = t & 1;
  const int R = c * 4 + 2 * u + (l >> 5);
  const int o = nq * 32 + (l & 31);
  unsigned int dwv[4];
#pragma unroll
  for (int jj = 0; jj < 8; ++jj) {
    int f, n;
    if (j < 8) { f = 8 * R + j;  n = jj; }
    else       { f = 8 * R + jj; n = 8;  }
    float v = (n < 8) ? coeffs[(f * 64 + o) * 8 + n] : bw[f * 64 + o];
    unsigned int hh = f2bf(v);
    if (jj & 1) dwv[jj >> 1] |= hh << 16; else dwv[jj >> 1] = hh;
  }
  uint4 qq; qq.x = dwv[0]; qq.y = dwv[1]; qq.z = dwv[2]; qq.w = dwv[3];
  Wsw[(g * 4 + t) * 64 + l] = qq;
}

#define MFMA32(A, B, C) __builtin_amdgcn_mfma_f32_32x32x16_bf16( \
    __builtin_bit_cast(short8, (A)), __builtin_bit_cast(short8, (B)), (C), 0, 0, 0)

// ---------------------------------------------------------------------------
// K2: 512 blocks x 512 thr. Block = 64 rows x 64 cols.
// Wave w: ks = w>>1 (basis slots {2ks,2ks+1}), mh = w&1 (rows 32mh..+32).
// Lane l: row = 32mh + (l&31); hi = l>>5 selects run parity (2u+hi).
// x-slot (qslot 8): waves ks in {0,1} handle u=ks, both nq fragments.
// A-fragments built in registers; zero main-loop barriers.
// LDS: P[4][64][64] f32 ks-partials (64 KB), single reduction barrier.
// ---------------------------------------------------------------------------
__global__ __launch_bounds__(512, 4) void wavelet_gemm(const float* __restrict__ x,
                                                       const uint4* __restrict__ Bsw,
                                                       float* __restrict__ out,
                                                       int out_size) {
  __shared__ float P[4 * 4096];      // 64 KB
  const int tid = threadIdx.x;
  const int l = tid & 63;
  const int w = tid >> 6;            // wave 0..7
  const int ks = w >> 1;             // basis slot pair {2ks, 2ks+1}
  const int mh = w & 1;              // row half
  const int hi = l >> 5;
  const int l31 = l & 31;
  const long rowbase = (long)blockIdx.x * 64;
  const float* xr = x + (rowbase + mh * 32 + l31) * 1024;
  const int sA = 2 * ks;             // first basis slot
  const int xduty = (ks < 2);        // x-slot owner: u = ks
  const int xrun = 2 * ks + hi;      // x-octet run_local (only used if xduty)

  f32x16 acc0 = {};                  // cols 0..31
  f32x16 acc1 = {};                  // cols 32..63

#pragma unroll 1
  for (int c = 0; c < 32; ++c) {
    const int cb = 32 * c;
    // ---- B fragments for this chunk's two basis slots (L2-hot) -----------
    const uint4* wp = Bsw + ((size_t)(c * 9 + sA) * 4) * 64 + l;
    uint4 BA0 = wp[0],   BA1 = wp[64],  BA2 = wp[128], BA3 = wp[192];
    uint4 BB0 = wp[256], BB1 = wp[320], BB2 = wp[384], BB3 = wp[448];
    // ---- x for the 4 basis features (one 128B line per lane per chunk) ---
    float2 f20 = *(const float2*)(xr + cb + 8 * hi + sA);         // run hi
    float2 f21 = *(const float2*)(xr + cb + 8 * (2 + hi) + sA);   // run 2+hi

    // ---- tanh/bucket for 4 basis features --------------------------------
    float xv[4] = {f20.x, f20.y, f21.x, f21.y};
    float t8v[4];
    unsigned int bad = 0;
#pragma unroll
    for (int ff = 0; ff < 4; ++ff) {
      float e = __expf(2.0f * xv[ff]);               // t8 = 8 - 8/(e+1)
      float r = __builtin_amdgcn_rcpf(e + 1.0f);
      float t8 = __builtin_fmaf(-8.0f, r, 8.0f);
      float rn = rintf(t8);
      if (fabsf(t8 - rn) < 3e-5f) bad |= 1u << ff;
      t8v[ff] = t8;
    }
    if (__builtin_expect(bad != 0, 0)) {
#pragma unroll
      for (int ff = 0; ff < 4; ++ff)
        if (bad & (1u << ff)) {
          float tf = (float)tanh((double)xv[ff]);    // ref-fidelity fallback
          t8v[ff] = ((tf + 1.0f) * 0.5f) * 8.0f;     // exact ref f32 pipeline
        }
    }
    // ---- A-fragments in registers: gen_basis output = lane's k-octet -----
    uint4 A[4];
#pragma unroll
    for (int ff = 0; ff < 4; ++ff) {
      int j = (int)t8v[ff]; j = j > 7 ? 7 : j;       // t8 in [0,8]
      unsigned int d[4];
      gen_basis(j, d);
      A[ff].x = d[0]; A[ff].y = d[1]; A[ff].z = d[2]; A[ff].w = d[3];
    }
    // slot sA:   u0 = A[0] (run hi),  u1 = A[2] (run 2+hi)
    acc0 = MFMA32(A[0], BA0, acc0);
    acc1 = MFMA32(A[0], BA1, acc1);
    acc0 = MFMA32(A[2], BA2, acc0);
    acc1 = MFMA32(A[2], BA3, acc1);
    // slot sA+1: u0 = A[1],           u1 = A[3]
    acc0 = MFMA32(A[1], BB0, acc0);
    acc1 = MFMA32(A[1], BB1, acc1);
    acc0 = MFMA32(A[3], BB2, acc0);
    acc1 = MFMA32(A[3], BB3, acc1);
    // ---- x-slot: wave ks in {0,1} owns u=ks, both nq ---------------------
    if (xduty) {
      const uint4* wx = Bsw + ((size_t)(c * 9 + 8) * 4) * 64 + l;
      uint4 BXa = wx[(2 * ks) * 64];         // t = 2u+0
      uint4 BXb = wx[(2 * ks + 1) * 64];     // t = 2u+1
      float4 xo0 = *(const float4*)(xr + cb + 8 * xrun);
      float4 xo1 = *(const float4*)(xr + cb + 8 * xrun + 4);
      uint4 xa;
      xa.x = f2bf(xo0.x) | (f2bf(xo0.y) << 16);
      xa.y = f2bf(xo0.z) | (f2bf(xo0.w) << 16);
      xa.z = f2bf(xo1.x) | (f2bf(xo1.y) << 16);
      xa.w = f2bf(xo1.z) | (f2bf(xo1.w) << 16);
      acc0 = MFMA32(xa, BXa, acc0);          // nq=0
      acc1 = MFMA32(xa, BXb, acc1);          // nq=1
    }
  }

  // ---- ks-partial store: P[ks][row][col]; 32x32 C/D layout:
  // col = lane&31, row = (reg&3) + 8*(reg>>2) + 4*(lane>>5).  (verified r7)
  float* Pk = P + ks * 4096;
  const int rbase = 32 * mh + 4 * hi;
#pragma unroll
  for (int rg = 0; rg < 16; ++rg) {
    const int grow = (rg & 3) + 8 * (rg >> 2) + rbase;
    Pk[grow * 64 + l31]      = acc0[rg];
    Pk[grow * 64 + 32 + l31] = acc1[rg];
  }
  __syncthreads();

  // ---- reduce 4 ks-partials, flat & conflict-free; coalesced store ------
  float* og = out + (size_t)rowbase * 64;
  const int d = tid * 4;
  f32x4 v0 = *(const f32x4*)(P + d) + *(const f32x4*)(P + 4096 + d)
           + *(const f32x4*)(P + 8192 + d) + *(const f32x4*)(P + 12288 + d);
  f32x4 v1 = *(const f32x4*)(P + 2048 + d) + *(const f32x4*)(P + 6144 + d)
           + *(const f32x4*)(P + 10240 + d) + *(const f32x4*)(P + 14336 + d);
  *(f32x4*)(og + d) = v0;
  *(f32x4*)(og + 2048 + d) = v1;
  if (blockIdx.x == 0 && tid == 0) out[out_size - 1] = 0.0f;  // kl = 0
}

extern "C" void kernel_launch(void* const* d_in, const int* in_sizes, int n_in,
                              void* d_out, int out_size, void* d_ws, size_t ws_size,
                              hipStream_t stream) {
  const float* x      = (const float*)d_in[0];   // [32768,1024] f32
  const float* coeffs = (const float*)d_in[1];   // [1024,64,8] f32
  const float* bw     = (const float*)d_in[2];   // [1024,64] f32
  uint4* Wsw = (uint4*)d_ws;                     // 288*4*64*16 = 1.125 MiB
  float* out = (float*)d_out;

  build_w<<<288, 256, 0, stream>>>(coeffs, bw, Wsw);
  wavelet_gemm<<<512, 512, 0, stream>>>(x, (const uint4*)Wsw, out, out_size);
}